// Round 1
// baseline (518.311 us; speedup 1.0000x reference)
//
#include <hip/hip_runtime.h>
#include <math.h>
#include <cstdint>
#include <cstddef>

// ---------------------------------------------------------------------------
// Transformer-XL relative multihead attention, MI355X (gfx950)
// S=1024, M=1024, T=2048, B=4, D=1024, H=16, DH=64
// Pipeline:
//   1. convert memory+x -> cbf (fp16), pos_emb -> posb (fp16)
//   2. transpose+convert W_qkv, W_rel, W_o -> [N][K] fp16
//   3. GEMM: qkv = cbf @ Wqkv  (8192x3072x1024, fp16 MFMA)
//   4. GEMM: r = posb @ Wrel   (2048x1024x1024)
//   5. transpose v slice -> vT[b][h][dh][t]
//   6. flash attention w/ rel-shift (BD[i,j] = (q_i+v)·r[j-i+1023])
//   7. GEMM: attn_out = av @ Wo (4096x1024x1024)
//   8. residual + LayerNorm -> fp32 out
// ---------------------------------------------------------------------------

typedef _Float16 half_t;
typedef _Float16 half8 __attribute__((ext_vector_type(8)));
typedef _Float16 half4v __attribute__((ext_vector_type(4)));
typedef float f32x4 __attribute__((ext_vector_type(4)));

#define S_LEN 1024
#define M_LEN 1024
#define T_LEN 2048
#define BATCH 4
#define NHEAD 16

// ---------------- fp32 -> fp16 convert (vectorized x4) ----------------
__global__ __launch_bounds__(256) void k_convert(const float* __restrict__ src,
                                                 half_t* __restrict__ dst, int n4) {
  int i = blockIdx.x * 256 + threadIdx.x;
  if (i >= n4) return;
  const float4 v = ((const float4*)src)[i];
  half4v h;
  h[0] = (half_t)v.x; h[1] = (half_t)v.y; h[2] = (half_t)v.z; h[3] = (half_t)v.w;
  ((half4v*)dst)[i] = h;
}

// ---------------- transpose + convert: src fp32 [R][C] -> dst fp16 [C][R] ----
__global__ __launch_bounds__(256) void k_transpose_w(const float* __restrict__ src,
                                                     half_t* __restrict__ dst,
                                                     int R, int C) {
  __shared__ float tile[64][65];
  const int t = threadIdx.x;
  const int r0 = blockIdx.x * 64, c0 = blockIdx.y * 64;
  const int tx = t & 63, ty4 = t >> 6;
#pragma unroll
  for (int k = 0; k < 16; ++k) {
    int row = k * 4 + ty4;
    tile[row][tx] = src[(size_t)(r0 + row) * C + c0 + tx];
  }
  __syncthreads();
#pragma unroll
  for (int k = 0; k < 16; ++k) {
    int orow = k * 4 + ty4;  // output row index = column c0+orow of src
    dst[(size_t)(c0 + orow) * R + r0 + tx] = (half_t)tile[tx][orow];
  }
}

// ---------------- fp16 GEMM: C[M][N] = A[M][K] @ BT[N][K]^T ----------------
// 128x128 tile, BK=64, 4 waves (2x2), each wave 64x64 via 4x4 mfma 16x16x32.
// LDS rows padded to 72 halfs (144B, 16B aligned, 2-way bank alias only).
__global__ __launch_bounds__(256) void k_gemm(const half_t* __restrict__ A,
                                              const half_t* __restrict__ B,
                                              half_t* __restrict__ C,
                                              int M, int N, int K) {
  __shared__ half_t ldsA[128][72];
  __shared__ half_t ldsB[128][72];
  const int t = threadIdx.x;
  const int wave = t >> 6, lane = t & 63, quad = lane >> 4, l15 = lane & 15;
  const int wm = (wave >> 1) * 64, wn = (wave & 1) * 64;
  const int m0 = blockIdx.x * 128, n0 = blockIdx.y * 128;
  f32x4 acc[4][4] = {};
  for (int k0 = 0; k0 < K; k0 += 64) {
    __syncthreads();
#pragma unroll
    for (int i = 0; i < 4; ++i) {
      const int ci = t + i * 256;
      const int row = ci >> 3, co = (ci & 7) * 8;
      *(half8*)&ldsA[row][co] = *(const half8*)&A[(size_t)(m0 + row) * K + k0 + co];
      *(half8*)&ldsB[row][co] = *(const half8*)&B[(size_t)(n0 + row) * K + k0 + co];
    }
    __syncthreads();
#pragma unroll
    for (int ks = 0; ks < 2; ++ks) {
      half8 af[4], bf[4];
#pragma unroll
      for (int mt = 0; mt < 4; ++mt)
        af[mt] = *(const half8*)&ldsA[wm + mt * 16 + l15][ks * 32 + quad * 8];
#pragma unroll
      for (int nt = 0; nt < 4; ++nt)
        bf[nt] = *(const half8*)&ldsB[wn + nt * 16 + l15][ks * 32 + quad * 8];
#pragma unroll
      for (int mt = 0; mt < 4; ++mt)
#pragma unroll
        for (int nt = 0; nt < 4; ++nt)
          acc[mt][nt] = __builtin_amdgcn_mfma_f32_16x16x32_f16(af[mt], bf[nt], acc[mt][nt], 0, 0, 0);
    }
  }
  // epilogue: C/D layout row = quad*4+reg, col = lane&15
#pragma unroll
  for (int mt = 0; mt < 4; ++mt)
#pragma unroll
    for (int nt = 0; nt < 4; ++nt)
#pragma unroll
      for (int r = 0; r < 4; ++r) {
        const int row = m0 + wm + mt * 16 + quad * 4 + r;
        const int col = n0 + wn + nt * 16 + l15;
        C[(size_t)row * N + col] = (half_t)acc[mt][nt][r];
      }
}

// ---------------- V transpose: qkv v-slice -> vT[(b*16+n)*64+dh][T] ----------
__global__ __launch_bounds__(256) void k_transpose_v(const half_t* __restrict__ qkv,
                                                     half_t* __restrict__ vT) {
  __shared__ half_t tile[64][72];
  const int t = threadIdx.x;
  const int t0 = blockIdx.x * 64, bn = blockIdx.y, b = bn >> 4, n = bn & 15;
#pragma unroll
  for (int i = 0; i < 2; ++i) {
    const int ci = t + i * 256;
    const int row = ci >> 3, co = (ci & 7) * 8;
    *(half8*)&tile[row][co] =
        *(const half8*)&qkv[((size_t)(t0 + row) * BATCH + b) * 3072 + 2048 + n * 64 + co];
  }
  __syncthreads();
#pragma unroll
  for (int i = 0; i < 2; ++i) {
    const int ci = t + i * 256;
    const int dh = ci >> 3, to = (ci & 7) * 8;
    half8 v;
#pragma unroll
    for (int j = 0; j < 8; ++j) v[j] = tile[to + j][dh];
    *(half8*)&vT[((size_t)bn * 64 + dh) * 2048 + t0 + to] = v;
  }
}

// ---------------- flash attention with Transformer-XL relative shift --------
// grid: (S/64, B*H). Block 256 = 4 waves; wave w owns queries [i0+16w, +16).
// BD[i,j] = (q_i + pos_bias_v) . r[j - i + 1023]  (valid region; masked else)
__global__ __launch_bounds__(256) void k_attn(const half_t* __restrict__ qkv,
                                              const half_t* __restrict__ rbuf,
                                              const half_t* __restrict__ vT,
                                              const float* __restrict__ pbu,
                                              const float* __restrict__ pbv,
                                              half_t* __restrict__ av) {
  __shared__ half_t ldsK[64][72];         // [key][dh]
  __shared__ half_t ldsV[64][72];         // [dh][key]
  __shared__ half_t ldsP[4][16][72];      // per-wave P, [qrow][key]
  __shared__ float  ldsE[4][16][84];      // per-wave E window, [qrow][p-col]
  const int t = threadIdx.x;
  const int wave = t >> 6, lane = t & 63, quad = lane >> 4, l15 = lane & 15;
  const int i0 = blockIdx.x * 64;
  const int bn = blockIdx.y, b = bn >> 4, n = bn & 15;
  const int i_base = i0 + wave * 16;

  // q fragments with biases folded in (loop-invariant across key tiles)
  half8 qu[2], qv[2];
#pragma unroll
  for (int ks = 0; ks < 2; ++ks) {
    const int dh0 = ks * 32 + quad * 8;
    const half8 qf = *(const half8*)&qkv[((size_t)(M_LEN + i_base + l15) * BATCH + b) * 3072 + n * 64 + dh0];
#pragma unroll
    for (int j = 0; j < 8; ++j) {
      const float qj = (float)qf[j];
      qu[ks][j] = (half_t)(qj + pbu[n * 64 + dh0 + j]);
      qv[ks][j] = (half_t)(qj + pbv[n * 64 + dh0 + j]);
    }
  }

  f32x4 oacc[4] = {};
  float m_old[4], l_sum[4];
#pragma unroll
  for (int r = 0; r < 4; ++r) { m_old[r] = -INFINITY; l_sum[r] = 0.f; }

  const int ntile = i0 / 64 + 17;  // keys up to i0+63+M inclusive, tiles of 64
  for (int kt = 0; kt < ntile; ++kt) {
    const int j0 = kt * 64;
    __syncthreads();  // prev-iter PV/score reads done before restaging
#pragma unroll
    for (int i = 0; i < 2; ++i) {
      const int ci = t + i * 256;
      const int row = ci >> 3, co = (ci & 7) * 8;
      *(half8*)&ldsK[row][co] =
          *(const half8*)&qkv[((size_t)(j0 + row) * BATCH + b) * 3072 + 1024 + n * 64 + co];
      *(half8*)&ldsV[row][co] =
          *(const half8*)&vT[((size_t)bn * 64 + row) * 2048 + j0 + co];
    }
    __syncthreads();

    // AC = (q+u) @ K^T
    f32x4 ac[4] = {};
#pragma unroll
    for (int ks = 0; ks < 2; ++ks)
#pragma unroll
      for (int nt = 0; nt < 4; ++nt) {
        const half8 kf = *(const half8*)&ldsK[nt * 16 + l15][ks * 32 + quad * 8];
        ac[nt] = __builtin_amdgcn_mfma_f32_16x16x32_f16(qu[ks], kf, ac[nt], 0, 0, 0);
      }

    // E window: E[m][c] = (q+v) . r[pw + c], pw = j0 + 1008 - i_base (width 80 >= 79)
    const int pw = j0 + 1008 - i_base;
    f32x4 ea[5] = {};
#pragma unroll
    for (int ks = 0; ks < 2; ++ks)
#pragma unroll
      for (int et = 0; et < 5; ++et) {
        int p = pw + et * 16 + l15;
        p = p < 0 ? 0 : (p > 2047 ? 2047 : p);  // clamp only hits masked cells
        const half8 rf = *(const half8*)&rbuf[(size_t)p * 1024 + n * 64 + ks * 32 + quad * 8];
        ea[et] = __builtin_amdgcn_mfma_f32_16x16x32_f16(qv[ks], rf, ea[et], 0, 0, 0);
      }
#pragma unroll
    for (int et = 0; et < 5; ++et)
#pragma unroll
      for (int r = 0; r < 4; ++r)
        ldsE[wave][quad * 4 + r][et * 16 + l15] = ea[et][r];
    __syncthreads();

    // scores + online softmax; shift: col' = cj + 15 - irow
#pragma unroll
    for (int r = 0; r < 4; ++r) {
      const int irow = quad * 4 + r;
      const int ig = i_base + irow;
      float svr[4];
      float rmax = -INFINITY;
#pragma unroll
      for (int nt = 0; nt < 4; ++nt) {
        const int cj = nt * 16 + l15;
        const float e = ldsE[wave][irow][cj + 15 - irow];
        float s = (ac[nt][r] + e) * 0.125f;
        if (j0 + cj > ig + M_LEN) s = -INFINITY;
        svr[nt] = s;
        rmax = fmaxf(rmax, s);
      }
#pragma unroll
      for (int off = 1; off < 16; off <<= 1) rmax = fmaxf(rmax, __shfl_xor(rmax, off));
      const float mn = fmaxf(m_old[r], rmax);
      const float al = exp2f((m_old[r] - mn) * 1.44269504088896f);
      float rs = 0.f;
#pragma unroll
      for (int nt = 0; nt < 4; ++nt) {
        const float p = exp2f((svr[nt] - mn) * 1.44269504088896f);
        rs += p;
        ldsP[wave][irow][nt * 16 + l15] = (half_t)p;
      }
#pragma unroll
      for (int off = 1; off < 16; off <<= 1) rs += __shfl_xor(rs, off);
      l_sum[r] = l_sum[r] * al + rs;
      m_old[r] = mn;
#pragma unroll
      for (int dnt = 0; dnt < 4; ++dnt) oacc[dnt][r] *= al;
    }
    __syncthreads();

    // PV: P (A-layout from LDS) @ V ([dh][key] -> B-frag contiguous)
    half8 pa[2];
#pragma unroll
    for (int ks = 0; ks < 2; ++ks)
      pa[ks] = *(const half8*)&ldsP[wave][l15][ks * 32 + quad * 8];
#pragma unroll
    for (int ks = 0; ks < 2; ++ks)
#pragma unroll
      for (int dnt = 0; dnt < 4; ++dnt) {
        const half8 vf = *(const half8*)&ldsV[dnt * 16 + l15][ks * 32 + quad * 8];
        oacc[dnt] = __builtin_amdgcn_mfma_f32_16x16x32_f16(pa[ks], vf, oacc[dnt], 0, 0, 0);
      }
  }

  // normalize and store av[(i*B+b)][n*64+dh] fp16
#pragma unroll
  for (int r = 0; r < 4; ++r) {
    const int ig = i_base + quad * 4 + r;
    const float inv = 1.0f / l_sum[r];
#pragma unroll
    for (int dnt = 0; dnt < 4; ++dnt)
      av[((size_t)ig * BATCH + b) * 1024 + n * 64 + dnt * 16 + l15] = (half_t)(oacc[dnt][r] * inv);
  }
}

// ---------------- residual + LayerNorm (one block per row) ----------------
__global__ __launch_bounds__(256) void k_ln(const float* __restrict__ x,
                                            const half_t* __restrict__ ao,
                                            const float* __restrict__ gamma,
                                            const float* __restrict__ beta,
                                            float* __restrict__ out) {
  const int row = blockIdx.x;
  const int t = threadIdx.x;
  const float4 xv = ((const float4*)(x + (size_t)row * 1024))[t];
  const half4v a4 = ((const half4v*)(ao + (size_t)row * 1024))[t];
  const float y0 = xv.x + (float)a4[0];
  const float y1 = xv.y + (float)a4[1];
  const float y2 = xv.z + (float)a4[2];
  const float y3 = xv.w + (float)a4[3];
  float s = y0 + y1 + y2 + y3;
  float ss = y0 * y0 + y1 * y1 + y2 * y2 + y3 * y3;
#pragma unroll
  for (int off = 1; off < 64; off <<= 1) {
    s += __shfl_xor(s, off);
    ss += __shfl_xor(ss, off);
  }
  __shared__ float sb[4], ssb[4];
  if ((t & 63) == 0) { sb[t >> 6] = s; ssb[t >> 6] = ss; }
  __syncthreads();
  s = sb[0] + sb[1] + sb[2] + sb[3];
  ss = ssb[0] + ssb[1] + ssb[2] + ssb[3];
  const float mean = s * (1.f / 1024.f);
  const float var = ss * (1.f / 1024.f) - mean * mean;
  const float rstd = rsqrtf(var + 1e-5f);
  const float4 g = ((const float4*)gamma)[t];
  const float4 be = ((const float4*)beta)[t];
  float4 o;
  o.x = (y0 - mean) * rstd * g.x + be.x;
  o.y = (y1 - mean) * rstd * g.y + be.y;
  o.z = (y2 - mean) * rstd * g.z + be.z;
  o.w = (y3 - mean) * rstd * g.w + be.w;
  ((float4*)(out + (size_t)row * 1024))[t] = o;
}

// ---------------------------------------------------------------------------
extern "C" void kernel_launch(void* const* d_in, const int* in_sizes, int n_in,
                              void* d_out, int out_size, void* d_ws, size_t ws_size,
                              hipStream_t stream) {
  const float* x     = (const float*)d_in[0];
  const float* pos   = (const float*)d_in[1];
  const float* pbu   = (const float*)d_in[2];
  const float* pbv   = (const float*)d_in[3];
  const float* mem   = (const float*)d_in[4];
  const float* Wqkv  = (const float*)d_in[5];
  const float* Wrel  = (const float*)d_in[6];
  const float* Wo    = (const float*)d_in[7];
  const float* gamma = (const float*)d_in[8];
  const float* beta  = (const float*)d_in[9];
  // d_in[10] (mask) unused: mask is analytically j > i + M
  float* out = (float*)d_out;

  half_t* ws    = (half_t*)d_ws;
  half_t* cbf   = ws;                 // [8192][1024]  concat(memory,x) fp16
  half_t* posb  = cbf + 8388608;      // [2048][1024]
  half_t* wqkvT = posb + 2097152;     // [3072][1024]
  half_t* wrelT = wqkvT + 3145728;    // [1024][1024]
  half_t* woT   = wrelT + 1048576;    // [1024][1024]
  half_t* qkv   = woT + 1048576;      // [8192][3072]
  half_t* rb    = qkv + 25165824;     // [2048][1024]
  half_t* vT    = rb + 2097152;       // [64][64][2048]
  half_t* av    = vT + 8388608;       // [4096][1024]
  half_t* aout  = qkv;                // reuse qkv region for attn_out [4096][1024]

  k_convert<<<4096, 256, 0, stream>>>(mem, cbf, 1048576);
  k_convert<<<4096, 256, 0, stream>>>(x, cbf + 4194304, 1048576);
  k_convert<<<2048, 256, 0, stream>>>(pos, posb, 524288);
  k_transpose_w<<<dim3(16, 48), 256, 0, stream>>>(Wqkv, wqkvT, 1024, 3072);
  k_transpose_w<<<dim3(16, 16), 256, 0, stream>>>(Wrel, wrelT, 1024, 1024);
  k_transpose_w<<<dim3(16, 16), 256, 0, stream>>>(Wo, woT, 1024, 1024);
  k_gemm<<<dim3(64, 24), 256, 0, stream>>>(cbf, wqkvT, qkv, 8192, 3072, 1024);
  k_gemm<<<dim3(16, 8), 256, 0, stream>>>(posb, wrelT, rb, 2048, 1024, 1024);
  k_transpose_v<<<dim3(32, 64), 256, 0, stream>>>(qkv, vT);
  k_attn<<<dim3(16, 64), 256, 0, stream>>>(qkv, rb, vT, pbu, pbv, av);
  k_gemm<<<dim3(32, 8), 256, 0, stream>>>(av, woT, aout, 4096, 1024, 1024);
  k_ln<<<4096, 256, 0, stream>>>(x, aout, gamma, beta, out);
}